// Round 8
// baseline (29.554 us; speedup 1.0000x reference)
//
#include <hip/hip_runtime.h>
#include <math.h>

// ChamferLossSplitPID: B=512, N=M=256, D=4, PIDs 0..3.
// out[0] = sum_b(sum_{p=1..3} loss_p)/B ; out[1+b] = (sum_{out_pid==0} |y|)/max(c0,1)/B
//
// R7: one wave per pid. Segments live in registers (4 tiers of 64/lane);
// the opposing point is broadcast via v_readlane (VALU) -> zero LDS traffic
// in the hot loop. Reduce kernel fused away via global atomicAdd + memset node.

constexpr int BATCH = 512;
constexpr int NP    = 256;
constexpr float INF2 = 1e30f;

__device__ __forceinline__ float rl(float v, int l) {
    return __int_as_float(__builtin_amdgcn_readlane(__float_as_int(v), l));
}

__device__ __forceinline__ float wave_reduce_add(float v) {
    #pragma unroll
    for (int off = 32; off > 0; off >>= 1)
        v += __shfl_xor(v, off, 64);
    return v;
}

// Scan: for each point j in the broadcast-side segment (tiers br[], count cb),
// update per-tier mins of the NXT lane-resident tiers xr[].
template<int NXT>
__device__ __forceinline__ void role_scan(const float4* xr, const float4 (&br)[4],
                                          int cb, float (&mn)[4]) {
    #pragma unroll
    for (int t = 0; t < 4; ++t) {
        if (cb > t * 64) {                       // wave-uniform
            const float4 Y = br[t];
            const int lim = (cb - t * 64 < 64) ? (cb - t * 64) : 64;
            for (int l = 0; l < lim; ++l) {      // wave-uniform trip count
                const float y0 = rl(Y.x, l), y1 = rl(Y.y, l),
                            y2 = rl(Y.z, l), y3 = rl(Y.w, l);
                #pragma unroll
                for (int u = 0; u < NXT; ++u) {
                    const float dx = xr[u].x - y0;
                    const float dy = xr[u].y - y1;
                    const float dz = xr[u].z - y2;
                    const float dw = xr[u].w - y3;
                    mn[u] = fminf(mn[u], dx * dx + dy * dy + dz * dz + dw * dw);
                }
            }
        }
    }
}

__global__ __launch_bounds__(256) void chamfer_pid_kernel(
    const float* __restrict__ target,   // [B, NP, 4]
    const float* __restrict__ reco,     // [B, NP, 4]
    const int*   __restrict__ in_pid,   // [B, NP]
    const int*   __restrict__ out_pid,  // [B, NP]
    float* __restrict__ out)            // [1 + B]
{
    const int b    = blockIdx.x;
    const int tid  = threadIdx.x;
    const int lane = tid & 63;
    const int p    = tid >> 6;          // wave index == owned pid

    __shared__ float4 sxs[NP], sys[NP];
    __shared__ int   s_cx[4], s_cy[4], s_offx[4], s_offy[4];
    __shared__ float s_sxy[4], s_syx[4], s_snx[4], s_sny[4];

    if (tid < 4) { s_cx[tid] = 0; s_cy[tid] = 0; }
    __syncthreads();

    const float4 xp = reinterpret_cast<const float4*>(target)[(size_t)b * NP + tid];
    const float4 yp = reinterpret_cast<const float4*>(reco)  [(size_t)b * NP + tid];
    const int pn = in_pid [(size_t)b * NP + tid];
    const int pm = out_pid[(size_t)b * NP + tid];

    const int slotx = atomicAdd(&s_cx[pn], 1);
    const int sloty = atomicAdd(&s_cy[pm], 1);
    __syncthreads();

    if (tid == 0) {
        int ox = 0, oy = 0;
        #pragma unroll
        for (int q = 0; q < 4; ++q) {
            s_offx[q] = ox; ox += s_cx[q];
            s_offy[q] = oy; oy += s_cy[q];
        }
    }
    __syncthreads();

    sxs[s_offx[pn] + slotx] = xp;
    sys[s_offy[pm] + sloty] = yp;
    __syncthreads();

    // ---- phase B: wave p owns pid p ----
    const int bx = s_offx[p], cx = s_cx[p];
    const int by = s_offy[p], cy = s_cy[p];

    float4 xr[4], yr[4];
    #pragma unroll
    for (int t = 0; t < 4; ++t) {
        const int ix = t * 64 + lane;
        xr[t] = (ix < cx) ? sxs[bx + ix] : make_float4(0.f, 0.f, 0.f, 0.f);
        yr[t] = (ix < cy) ? sys[by + ix] : make_float4(0.f, 0.f, 0.f, 0.f);
    }

    float mina[4] = {INF2, INF2, INF2, INF2};   // per x-point min d2
    float minb[4] = {INF2, INF2, INF2, INF2};   // per y-point min d2

    if (p >= 1) {
        const int xt = (cx + 63) >> 6;
        if (xt <= 1)      role_scan<1>(xr, yr, cy, mina);
        else if (xt == 2) role_scan<2>(xr, yr, cy, mina);
        else              role_scan<4>(xr, yr, cy, mina);

        const int yt = (cy + 63) >> 6;
        if (yt <= 1)      role_scan<1>(yr, xr, cx, minb);
        else if (yt == 2) role_scan<2>(yr, xr, cx, minb);
        else              role_scan<4>(yr, xr, cx, minb);
    }

    // per-lane partial sums: norms + sqrt(min d2) (sqrt(min) == min dist)
    float nxsum = 0.f, nysum = 0.f, sxysum = 0.f, syxsum = 0.f;
    #pragma unroll
    for (int t = 0; t < 4; ++t) {
        const int ix = t * 64 + lane;
        if (ix < cx) {
            nxsum  += sqrtf(xr[t].x * xr[t].x + xr[t].y * xr[t].y +
                            xr[t].z * xr[t].z + xr[t].w * xr[t].w);
            sxysum += sqrtf(mina[t]);
        }
        if (ix < cy) {
            nysum  += sqrtf(yr[t].x * yr[t].x + yr[t].y * yr[t].y +
                            yr[t].z * yr[t].z + yr[t].w * yr[t].w);
            syxsum += sqrtf(minb[t]);
        }
    }

    sxysum = wave_reduce_add(sxysum);
    syxsum = wave_reduce_add(syxsum);
    nxsum  = wave_reduce_add(nxsum);
    nysum  = wave_reduce_add(nysum);

    if (lane == 0) {            // single writer per pid slot, no atomics
        s_sxy[p] = sxysum; s_syx[p] = syxsum;
        s_snx[p] = nxsum;  s_sny[p] = nysum;
    }
    __syncthreads();

    if (tid == 0) {
        float nonzero = 0.0f;
        #pragma unroll
        for (int q = 1; q < 4; ++q) {
            const int cxq = s_cx[q];
            const int cyq = s_cy[q];
            const float n_in  = (float)(cxq > 1 ? cxq : 1);
            const float n_out = (float)(cyq > 1 ? cyq : 1);
            float loss;
            if (cyq == 0) {
                loss = s_snx[q] / n_in;
            } else if (cxq == 0) {
                loss = s_sny[q] / n_out;
            } else {
                loss = 0.5f * (s_sxy[q] / n_out + s_syx[q] / n_in);
            }
            nonzero += loss;
        }
        atomicAdd(out, nonzero * (1.0f / (float)BATCH));

        const int c0 = s_cy[0];
        const float c0f = (float)(c0 > 1 ? c0 : 1);
        out[1 + b] = (s_sny[0] / c0f) / (float)BATCH;
    }
}

extern "C" void kernel_launch(void* const* d_in, const int* in_sizes, int n_in,
                              void* d_out, int out_size, void* d_ws, size_t ws_size,
                              hipStream_t stream) {
    const float* target  = (const float*)d_in[0];
    const float* reco    = (const float*)d_in[1];
    const int*   in_pid  = (const int*)d_in[2];
    const int*   out_pid = (const int*)d_in[3];
    float* out = (float*)d_out;

    // re-zero the atomic accumulator each call (graph-captures as a memset node)
    hipMemsetAsync(out, 0, sizeof(float), stream);
    chamfer_pid_kernel<<<BATCH, 256, 0, stream>>>(target, reco, in_pid, out_pid, out);
}

// Round 9
// 16.710 us; speedup vs baseline: 1.7686x; 1.7686x over previous
//
#include <hip/hip_runtime.h>
#include <math.h>

// ChamferLossSplitPID: B=512, N=M=256, D=4, PIDs 0..3.
// out[0] = sum_b(sum_{p=1..3} loss_p)/B ; out[1+b] = (sum_{out_pid==0} |y|)/max(c0,1)/B
//
// R9: pid-scatter into LDS, then SORTED-thread mapping (thread k owns sorted
// point k) -> wave-coherent trip counts, broadcast LDS reads, balanced waves.
// 512 threads/block: half x-role, half y-role. Inner loop unrolled 4x for ILP.

constexpr int BATCH = 512;
constexpr int NP    = 256;
constexpr float INF2 = 1e30f;

__device__ __forceinline__ float dist2_f4(const float4 a, const float4 b) {
    const float dx = a.x - b.x;
    const float dy = a.y - b.y;
    const float dz = a.z - b.z;
    const float dw = a.w - b.w;
    return dx * dx + dy * dy + dz * dz + dw * dw;
}

__device__ __forceinline__ float min_scan(const float4 xp, const float4* seg, int cnt) {
    float m0 = INF2, m1 = INF2, m2 = INF2, m3 = INF2;
    int j = 0;
    for (; j + 4 <= cnt; j += 4) {      // 4 independent LDS loads + dist chains
        const float4 A = seg[j], B = seg[j + 1], C = seg[j + 2], D = seg[j + 3];
        m0 = fminf(m0, dist2_f4(xp, A));
        m1 = fminf(m1, dist2_f4(xp, B));
        m2 = fminf(m2, dist2_f4(xp, C));
        m3 = fminf(m3, dist2_f4(xp, D));
    }
    for (; j < cnt; ++j) m0 = fminf(m0, dist2_f4(xp, seg[j]));
    return fminf(fminf(m0, m1), fminf(m2, m3));
}

__global__ __launch_bounds__(512) void chamfer_pid_kernel(
    const float* __restrict__ target,   // [B, NP, 4]
    const float* __restrict__ reco,     // [B, NP, 4]
    const int*   __restrict__ in_pid,   // [B, NP]
    const int*   __restrict__ out_pid,  // [B, NP]
    float* __restrict__ out,            // [1 + B]
    float* __restrict__ ws)             // [B] per-batch nonzero loss
{
    const int b    = blockIdx.x;
    const int tid  = threadIdx.x;
    const int k    = tid & (NP - 1);
    const int half = tid >> 8;          // 0: x-role, 1: y-role

    __shared__ float4 sxs[NP], sys[NP];
    __shared__ int   s_cx[4], s_cy[4], s_offx[4], s_offy[4];
    __shared__ float s_sxy[4], s_syx[4], s_snx[4], s_sny[4];

    if (tid < 4) {
        s_cx[tid] = 0;    s_cy[tid] = 0;
        s_sxy[tid] = 0.f; s_syx[tid] = 0.f;
        s_snx[tid] = 0.f; s_sny[tid] = 0.f;
    }
    __syncthreads();

    // ---- load + slot-grab (half 0 loads x, half 1 loads y) ----
    float4 pt;
    int pid, slot;
    if (half == 0) {
        pt  = reinterpret_cast<const float4*>(target)[(size_t)b * NP + k];
        pid = in_pid[(size_t)b * NP + k];
        slot = atomicAdd(&s_cx[pid], 1);
    } else {
        pt  = reinterpret_cast<const float4*>(reco)[(size_t)b * NP + k];
        pid = out_pid[(size_t)b * NP + k];
        slot = atomicAdd(&s_cy[pid], 1);
    }
    __syncthreads();

    if (tid == 0) {
        int ox = 0, oy = 0;
        #pragma unroll
        for (int q = 0; q < 4; ++q) {
            s_offx[q] = ox; ox += s_cx[q];
            s_offy[q] = oy; oy += s_cy[q];
        }
    }
    __syncthreads();

    if (half == 0) sxs[s_offx[pid] + slot] = pt;
    else           sys[s_offy[pid] + slot] = pt;
    __syncthreads();

    // ---- phase B: thread k owns SORTED point k (wave-coherent pid) ----
    if (half == 0) {
        const int p = (k >= s_offx[1]) + (k >= s_offx[2]) + (k >= s_offx[3]);
        const float4 xp = sxs[k];
        if (p >= 1) {
            const float nrm = sqrtf(xp.x * xp.x + xp.y * xp.y + xp.z * xp.z + xp.w * xp.w);
            atomicAdd(&s_snx[p], nrm);
            const int cnt = s_cy[p];
            if (cnt > 0) {
                const float mn = min_scan(xp, (const float4*)&sys[s_offy[p]], cnt);
                atomicAdd(&s_sxy[p], sqrtf(mn));   // sqrt(min d2) == min dist
            }
        }
    } else {
        const int p = (k >= s_offy[1]) + (k >= s_offy[2]) + (k >= s_offy[3]);
        const float4 yp = sys[k];
        const float nrm = sqrtf(yp.x * yp.x + yp.y * yp.y + yp.z * yp.z + yp.w * yp.w);
        atomicAdd(&s_sny[p], nrm);                 // pid 0 needed for output 1
        if (p >= 1) {
            const int cnt = s_cx[p];
            if (cnt > 0) {
                const float mn = min_scan(yp, (const float4*)&sxs[s_offx[p]], cnt);
                atomicAdd(&s_syx[p], sqrtf(mn));
            }
        }
    }
    __syncthreads();

    if (tid == 0) {
        float nonzero = 0.0f;
        #pragma unroll
        for (int q = 1; q < 4; ++q) {
            const int cxq = s_cx[q];
            const int cyq = s_cy[q];
            const float n_in  = (float)(cxq > 1 ? cxq : 1);
            const float n_out = (float)(cyq > 1 ? cyq : 1);
            float loss;
            if (cyq == 0) {
                loss = s_snx[q] / n_in;
            } else if (cxq == 0) {
                loss = s_sny[q] / n_out;
            } else {
                loss = 0.5f * (s_sxy[q] / n_out + s_syx[q] / n_in);
            }
            nonzero += loss;
        }
        ws[b] = nonzero;

        const int c0 = s_cy[0];
        const float c0f = (float)(c0 > 1 ? c0 : 1);
        out[1 + b] = (s_sny[0] / c0f) / (float)BATCH;
    }
}

__global__ __launch_bounds__(256) void chamfer_reduce_kernel(
    const float* __restrict__ ws,  // [B]
    float* __restrict__ out)       // out[0]
{
    __shared__ float red[256];
    const int i = threadIdx.x;
    red[i] = ws[i] + ws[i + 256];
    __syncthreads();
    #pragma unroll
    for (int s = 128; s > 0; s >>= 1) {
        if (i < s) red[i] += red[i + s];
        __syncthreads();
    }
    if (i == 0) {
        out[0] = red[0] / (float)BATCH;
    }
}

extern "C" void kernel_launch(void* const* d_in, const int* in_sizes, int n_in,
                              void* d_out, int out_size, void* d_ws, size_t ws_size,
                              hipStream_t stream) {
    const float* target  = (const float*)d_in[0];
    const float* reco    = (const float*)d_in[1];
    const int*   in_pid  = (const int*)d_in[2];
    const int*   out_pid = (const int*)d_in[3];
    float* out = (float*)d_out;
    float* ws  = (float*)d_ws;

    chamfer_pid_kernel<<<BATCH, 512, 0, stream>>>(target, reco, in_pid, out_pid, out, ws);
    chamfer_reduce_kernel<<<1, 256, 0, stream>>>(ws, out);
}